// Round 9
// baseline (1625.883 us; speedup 1.0000x reference)
//
#include <hip/hip_runtime.h>
#include <math.h>

#define BATCH 4096
#define TT 48
#define DDIM 59
#define HHID 256
#define RR 16              // batch rows per workgroup
#define NWG (BATCH/RR)     // 256 workgroups (1 per CU)
#define NTHR 512           // 8 waves

typedef _Float16 f16;
typedef _Float16 f16x8 __attribute__((ext_vector_type(8)));
typedef float    f32x4 __attribute__((ext_vector_type(4)));

// ---- output layout (floats) ----
static constexpr size_t N_XIMP   = (size_t)BATCH*TT*DDIM;
static constexpr size_t OFF_LOSS = N_XIMP;
static constexpr size_t OFF_HS   = OFF_LOSS + 1;
static constexpr size_t N_HS     = (size_t)BATCH*TT*HHID;
static constexpr size_t OFF_YOUT = OFF_HS + N_HS;
static constexpr size_t OFF_YSC  = OFF_YOUT + BATCH;
static constexpr size_t OFF_DEC  = OFF_YSC + BATCH;

// ---- f16 weight workspace layout (element offsets from wbase) ----
static constexpr size_t WOFF_GRU  = 0;          // 16 jb * 36 blocks
static constexpr size_t WOFF_DH   = 294912;     // 16 nt * 2 kt
static constexpr size_t WOFF_HIST = 311296;     // 4 nt * 8 kt
static constexpr size_t WOFF_FEAT = 327680;     // 4 nt * 2 kt
static constexpr size_t WOFF_WC   = 331776;     // 4 nt * 4 kt

__device__ __forceinline__ float sigm(float v){ return 1.f/(1.f+expf(-v)); }

// =====================================================================
// decay_factor (fully parallel)
// =====================================================================
__global__ __launch_bounds__(256) void decay_kernel(
    const float* __restrict__ deltas, const float* __restrict__ medians,
    const float* __restrict__ wobs_W, const float* __restrict__ wobs_b,
    float* __restrict__ out_decay)
{
  __shared__ float sW[DDIM][60];
  __shared__ float sb[64], smed[64];
  __shared__ float sdd[16][60];
  const int tid = threadIdx.x;
  for (int idx = tid; idx < DDIM*DDIM; idx += 256){
    int e = idx/DDIM, d = idx - e*DDIM;
    sW[e][d] = wobs_W[idx];
  }
  if (tid < DDIM){ sb[tid] = wobs_b[tid]; smed[tid] = medians[tid]; }
  __syncthreads();
  const size_t row0 = (size_t)blockIdx.x * 16;
  for (int idx = tid; idx < 16*DDIM; idx += 256){
    int r = idx/DDIM, d = idx - r*DDIM;
    sdd[r][d] = __builtin_nontemporal_load(&deltas[(row0+r)*DDIM + d]) - smed[d];
  }
  __syncthreads();
  for (int idx = tid; idx < 16*DDIM; idx += 256){
    int r = idx/DDIM, e = idx - r*DDIM;
    float acc = sb[e];
    for (int d = 0; d < DDIM; d++) acc += sdd[r][d]*sW[e][d];
    float dd = sdd[r][e];
    float sg = (dd > 0.f) ? 1.f : ((dd < 0.f) ? -1.f : 0.f);
    out_decay[(row0+r)*DDIM + e] = 0.5f*(1.f - tanhf(sg*fabsf(acc)));
  }
}

// =====================================================================
// Weight conversion: fp32 -> f16 MFMA B-fragment blocks (unchanged)
// =====================================================================
__global__ __launch_bounds__(256) void conv_kernel(
    const float* __restrict__ W_dh, const float* __restrict__ hist_W,
    const float* __restrict__ feat_W, const float* __restrict__ wcomb_W,
    const float* __restrict__ W_ih, const float* __restrict__ W_hh,
    f16* __restrict__ ws)
{
  const int g  = blockIdx.x*4 + (threadIdx.x >> 6);
  const int l  = threadIdx.x & 63;
  const int nl = l & 15;
  const int kh = (l >> 4) * 8;
  f16x8 out;
  if (g < 576){                                   // GRU
    int jb = g/36, s = g - jb*36;
    if (s < 24){                                  // r or z (fused ih+hh)
      int gate = s/12, kt = s - gate*12;
      int row  = gate*256 + jb*16 + nl;
      #pragma unroll
      for (int e = 0; e < 8; e++){
        int k = kt*32 + kh + e;
        float v = (k < 256) ? W_hh[(size_t)row*256 + k]
                : (k < 374) ? W_ih[(size_t)row*118 + (k-256)] : 0.f;
        out[e] = (f16)v;
      }
    } else if (s < 32){                           // n-gate hidden part
      int kt = s - 24, row = 512 + jb*16 + nl;
      #pragma unroll
      for (int e = 0; e < 8; e++){
        int k = kt*32 + kh + e;
        out[e] = (f16)W_hh[(size_t)row*256 + k];
      }
    } else {                                      // n-gate input part
      int kt = s - 32, row = 512 + jb*16 + nl;
      #pragma unroll
      for (int e = 0; e < 8; e++){
        int k = kt*32 + kh + e;
        out[e] = (f16)((k < 118) ? W_ih[(size_t)row*118 + k] : 0.f);
      }
    }
    *(f16x8*)&ws[WOFF_GRU + (size_t)g*512 + l*8] = out;
  } else if (g < 608){                            // gamma_h decay W_dh
    int i = g - 576, nt = i >> 1, kt = i & 1;
    int row = nt*16 + nl;
    #pragma unroll
    for (int e = 0; e < 8; e++){
      int k = kt*32 + kh + e;
      out[e] = (f16)((k < 59) ? W_dh[(size_t)row*59 + k] : 0.f);
    }
    *(f16x8*)&ws[WOFF_DH + (size_t)i*512 + l*8] = out;
  } else if (g < 640){                            // hist_W
    int i = g - 608, nt = i >> 3, kt = i & 7;
    int n = nt*16 + nl;
    #pragma unroll
    for (int e = 0; e < 8; e++){
      int k = kt*32 + kh + e;
      out[e] = (f16)((n < 59) ? hist_W[(size_t)n*256 + k] : 0.f);
    }
    *(f16x8*)&ws[WOFF_HIST + (size_t)i*512 + l*8] = out;
  } else if (g < 648){                            // feat_W (off-diag mask baked in)
    int i = g - 640, nt = i >> 1, kt = i & 1;
    int n = nt*16 + nl;
    #pragma unroll
    for (int e = 0; e < 8; e++){
      int k = kt*32 + kh + e;
      out[e] = (f16)((n < 59 && k < 59 && k != n) ? feat_W[(size_t)n*59 + k] : 0.f);
    }
    *(f16x8*)&ws[WOFF_FEAT + (size_t)i*512 + l*8] = out;
  } else {                                        // wcomb_W
    int i = g - 648, nt = i >> 2, kt = i & 3;
    int n = nt*16 + nl;
    #pragma unroll
    for (int e = 0; e < 8; e++){
      int k = kt*32 + kh + e;
      out[e] = (f16)((n < 59 && k < 118) ? wcomb_W[(size_t)n*118 + k] : 0.f);
    }
    *(f16x8*)&ws[WOFF_WC + (size_t)i*512 + l*8] = out;
  }
}

// =====================================================================
// Sequential scan: 8 waves, RR=16, NWG=256, high-VGPR deep-prefetch.
// Wave w owns GRU jb slices 2w, 2w+1 and gamma_h n-tiles 2w, 2w+1.
// A-frags ds_read once (aH[8]) and reused across r/z/nh/x_h.
// B-frags batch-loaded into registers before MFMA blocks (MLP).
// Phases: P0 stage+hs(t-1) | P1 gamma_h | P2 GRU-h + x_h + beta |
//         P3 feat (in-reg A) | P4 x_comb/loss | P5 GRU finish
// =====================================================================
__global__ __launch_bounds__(NTHR, 2) void seq_kernel(
    const float* __restrict__ x, const float* __restrict__ mask,
    const float* __restrict__ deltas, const float* __restrict__ h0,
    const float* __restrict__ b_dh, const float* __restrict__ W_dx,
    const float* __restrict__ b_dx, const float* __restrict__ hist_b,
    const float* __restrict__ feat_b, const float* __restrict__ wcomb_b,
    const float* __restrict__ b_ih, const float* __restrict__ b_hh,
    const f16* __restrict__ wb,
    float* __restrict__ out_ximp, float* __restrict__ out_hs,
    float* __restrict__ ws_num, float* __restrict__ ws_den)
{
  __shared__ f16 Acat[RR*392];    // [h(0:256) | x_imp(256:315) | m(315:374) | pad]
  __shared__ f16 Ad  [RR*72];     // deltas; pad 59:72
  __shared__ f16 Agm [RR*136];    // [gamma_x(0:59) | m(59:118) | pad]
  __shared__ f16 ssx [RR*60];     // x
  __shared__ f16 sxh [RR*60];     // x_h
  __shared__ f16 sxu [RR*60];     // feat output
  __shared__ f16 sbt [RR*60];     // beta
  __shared__ float sh [RR*260];   // fp32 hidden state
  __shared__ float sredN[8], sredD[8];

  const int tid = threadIdx.x;
  const int w   = tid >> 6;          // 0..7
  const int l   = tid & 63;
  const int nl  = l & 15;
  const int kh  = (l >> 4) * 8;
  const int mq  = (l >> 4) * 4;
  const int row0 = blockIdx.x * RR;

  const f16* Bgru  = wb + WOFF_GRU;
  const f16* Bdh   = wb + WOFF_DH;
  const f16* Bhist = wb + WOFF_HIST;
  const f16* Bfeat = wb + WOFF_FEAT;
  const f16* Bwc   = wb + WOFF_WC;

  // staging slots (2 cover 944)
  const int r0s = tid/59,        d0s = tid - r0s*59;
  const int i1  = tid + NTHR;
  const int r1s = i1/59,         d1s = i1 - r1s*59;
  const bool has1 = (i1 < RR*DDIM);

  // per-thread diag-decay constants for the 2 slots (hoisted from W_dx)
  const float dg0 = W_dx[(size_t)d0s*DDIM + d0s], bx0 = b_dx[d0s];
  const float dg1 = has1 ? W_dx[(size_t)d1s*DDIM + d1s] : 0.f;
  const float bx1 = has1 ? b_dx[d1s] : 0.f;

  // per-wave biases: gamma_h tiles & GRU gate rows (jb = 2w+ii)
  float bdh_i[2], br_j[2], bz_j[2], bni_j[2], bnh_j[2];
  #pragma unroll
  for (int ii = 0; ii < 2; ii++){
    int n = (2*w+ii)*16 + nl;
    bdh_i[ii] = b_dh[n];
    br_j[ii]  = b_ih[n]     + b_hh[n];
    bz_j[ii]  = b_ih[256+n] + b_hh[256+n];
    bni_j[ii] = b_ih[512+n];
    bnh_j[ii] = b_hh[512+n];
  }
  const int nA = w*16 + nl;                       // waves 0-3: x_h/feat col
  const int nB = (w-4)*16 + nl;                   // waves 4-7: beta col
  const float hb_n = (w < 4 && nA < DDIM) ? hist_b[nA] : 0.f;
  const float fb_n = (w < 4 && nA < DDIM) ? feat_b[nA] : 0.f;
  const float cb_n = (w >= 4 && nB < DDIM) ? wcomb_b[nB] : 0.f;

  // hs-write entries (2 per thread: rows 0-7, 8-15)
  const int hrowA = tid >> 6;          // 0..7
  const int hrowB = hrowA + 8;
  const int hj0   = (tid & 63) * 4;
  float* hsA = out_hs + (size_t)(row0+hrowA)*TT*HHID + hj0;
  float* hsB = out_hs + (size_t)(row0+hrowB)*TT*HHID + hj0;

  // zero pads once
  for (int idx = tid; idx < RR*18; idx += NTHR){
    int r = idx/18, c = idx - (idx/18)*18;
    Acat[r*392 + 374 + c] = (f16)0.f;
    Agm [r*136 + 118 + c] = (f16)0.f;
  }
  for (int idx = tid; idx < RR*13; idx += NTHR){
    int r = idx/13, c = idx - (idx/13)*13;
    Ad[r*72 + 59 + c] = (f16)0.f;
  }
  for (int idx = tid; idx < RR*HHID; idx += NTHR){
    int r = idx >> 8, j = idx & 255;
    sh[r*260 + j] = h0[(size_t)(row0+r)*HHID + j];
  }

  // prologue prefetch (t = 0)
  float vx0, vm0, vd0, vx1 = 0.f, vm1 = 0.f, vd1 = 0.f;
  {
    size_t g0 = ((size_t)(row0+r0s)*TT)*DDIM + d0s;
    vx0 = __builtin_nontemporal_load(&x[g0]);
    vm0 = __builtin_nontemporal_load(&mask[g0]);
    vd0 = __builtin_nontemporal_load(&deltas[g0]);
    if (has1){
      size_t g1 = ((size_t)(row0+r1s)*TT)*DDIM + d1s;
      vx1 = __builtin_nontemporal_load(&x[g1]);
      vm1 = __builtin_nontemporal_load(&mask[g1]);
      vd1 = __builtin_nontemporal_load(&deltas[g1]);
    }
  }
  __syncthreads();

  for (int t = 0; t < TT; t++){
    // ---- P0: stage x/m/d + gamma_x (register-direct) + hs(t-1) write ----
    {
      ssx[r0s*60+d0s]     = (f16)vx0;
      Ad [r0s*72+d0s]     = (f16)vd0;
      Agm[r0s*136+59+d0s] = (f16)vm0;
      Acat[r0s*392+315+d0s] = (f16)vm0;
      Agm[r0s*136+d0s]    = (f16)expf(-fmaxf(vd0*dg0 + bx0, 0.f));
      if (has1){
        ssx[r1s*60+d1s]     = (f16)vx1;
        Ad [r1s*72+d1s]     = (f16)vd1;
        Agm[r1s*136+59+d1s] = (f16)vm1;
        Acat[r1s*392+315+d1s] = (f16)vm1;
        Agm[r1s*136+d1s]    = (f16)expf(-fmaxf(vd1*dg1 + bx1, 0.f));
      }
      if (t > 0){
        f32x4 va, vb;
        #pragma unroll
        for (int c = 0; c < 4; c++){ va[c] = sh[hrowA*260 + hj0 + c]; vb[c] = sh[hrowB*260 + hj0 + c]; }
        __builtin_nontemporal_store(va, (f32x4*)(hsA + (size_t)(t-1)*HHID));
        __builtin_nontemporal_store(vb, (f32x4*)(hsB + (size_t)(t-1)*HHID));
      }
    }
    __syncthreads();

    // issue next step's input loads (latency hidden under compute)
    if (t + 1 < TT){
      size_t g0 = ((size_t)(row0+r0s)*TT + (t+1))*DDIM + d0s;
      vx0 = __builtin_nontemporal_load(&x[g0]);
      vm0 = __builtin_nontemporal_load(&mask[g0]);
      vd0 = __builtin_nontemporal_load(&deltas[g0]);
      if (has1){
        size_t g1 = ((size_t)(row0+r1s)*TT + (t+1))*DDIM + d1s;
        vx1 = __builtin_nontemporal_load(&x[g1]);
        vm1 = __builtin_nontemporal_load(&mask[g1]);
        vd1 = __builtin_nontemporal_load(&deltas[g1]);
      }
    }

    // ---- P1: gamma_h MFMA (wave w -> n-tiles 2w, 2w+1) ----
    {
      f16x8 a0 = *(const f16x8*)&Ad[nl*72 + kh];
      f16x8 a1 = *(const f16x8*)&Ad[nl*72 + 32 + kh];
      #pragma unroll
      for (int ii = 0; ii < 2; ii++){
        int nt = 2*w + ii;
        f16x8 b0 = *(const f16x8*)&Bdh[(size_t)(nt*2+0)*512 + l*8];
        f16x8 b1 = *(const f16x8*)&Bdh[(size_t)(nt*2+1)*512 + l*8];
        f32x4 acc = {0.f,0.f,0.f,0.f};
        acc = __builtin_amdgcn_mfma_f32_16x16x32_f16(a0, b0, acc, 0, 0, 0);
        acc = __builtin_amdgcn_mfma_f32_16x16x32_f16(a1, b1, acc, 0, 0, 0);
        int n = nt*16 + nl;
        #pragma unroll
        for (int q = 0; q < 4; q++){
          float gm = expf(-fmaxf(acc[q] + bdh_i[ii], 0.f));
          float hv = sh[(mq+q)*260 + n] * gm;
          sh[(mq+q)*260 + n] = hv;
          Acat[(mq+q)*392 + n] = (f16)hv;
        }
      }
    }
    __syncthreads();

    // ---- P2: GRU-h (2 jb/wave, kt0-7) + x_h (w<4) + beta (w>=4) ----
    f32x4 gr[2], gz[2], gnh[2];
    {
      f16x8 aH[8];
      #pragma unroll
      for (int kt = 0; kt < 8; kt++)
        aH[kt] = *(const f16x8*)&Acat[nl*392 + kt*32 + kh];

      #pragma unroll
      for (int jj = 0; jj < 2; jj++){
        const f16* Bb = Bgru + (size_t)(2*w+jj)*36*512;
        f16x8 br[8], bz[8], bn[8];
        #pragma unroll
        for (int kt = 0; kt < 8; kt++){
          br[kt] = *(const f16x8*)&Bb[(size_t)kt*512 + l*8];
          bz[kt] = *(const f16x8*)&Bb[(size_t)(12+kt)*512 + l*8];
          bn[kt] = *(const f16x8*)&Bb[(size_t)(24+kt)*512 + l*8];
        }
        f32x4 r_ = {0.f,0.f,0.f,0.f}, z_ = {0.f,0.f,0.f,0.f}, n_ = {0.f,0.f,0.f,0.f};
        #pragma unroll
        for (int kt = 0; kt < 8; kt++){
          r_ = __builtin_amdgcn_mfma_f32_16x16x32_f16(aH[kt], br[kt], r_, 0, 0, 0);
          z_ = __builtin_amdgcn_mfma_f32_16x16x32_f16(aH[kt], bz[kt], z_, 0, 0, 0);
          n_ = __builtin_amdgcn_mfma_f32_16x16x32_f16(aH[kt], bn[kt], n_, 0, 0, 0);
        }
        gr[jj] = r_; gz[jj] = z_; gnh[jj] = n_;
      }

      if (w < 4){                               // x_h (reuses aH)
        f16x8 bh[8];
        #pragma unroll
        for (int kt = 0; kt < 8; kt++)
          bh[kt] = *(const f16x8*)&Bhist[(size_t)(w*8+kt)*512 + l*8];
        f32x4 acc = {0.f,0.f,0.f,0.f};
        #pragma unroll
        for (int kt = 0; kt < 8; kt++)
          acc = __builtin_amdgcn_mfma_f32_16x16x32_f16(aH[kt], bh[kt], acc, 0, 0, 0);
        if (nA < DDIM){
          #pragma unroll
          for (int q = 0; q < 4; q++) sxh[(mq+q)*60 + nA] = (f16)(acc[q] + hb_n);
        }
      } else {                                  // beta
        f16x8 aG[4], bw[4];
        #pragma unroll
        for (int kt = 0; kt < 4; kt++){
          aG[kt] = *(const f16x8*)&Agm[nl*136 + kt*32 + kh];
          bw[kt] = *(const f16x8*)&Bwc[(size_t)((w-4)*4+kt)*512 + l*8];
        }
        f32x4 acc = {0.f,0.f,0.f,0.f};
        #pragma unroll
        for (int kt = 0; kt < 4; kt++)
          acc = __builtin_amdgcn_mfma_f32_16x16x32_f16(aG[kt], bw[kt], acc, 0, 0, 0);
        if (nB < DDIM){
          #pragma unroll
          for (int q = 0; q < 4; q++) sbt[(mq+q)*60 + nB] = (f16)sigm(acc[q] + cb_n);
        }
      }
    }
    __syncthreads();

    // ---- P3: feat (waves 0-3; x_r A-frag assembled in-register) ----
    if (w < 4){
      f16x8 bf0 = *(const f16x8*)&Bfeat[(size_t)(w*2+0)*512 + l*8];
      f16x8 bf1 = *(const f16x8*)&Bfeat[(size_t)(w*2+1)*512 + l*8];
      f16x8 a0, a1;
      #pragma unroll
      for (int e = 0; e < 8; e++){
        int c0 = kh + e;            // kt=0
        int c1 = 32 + kh + e;       // kt=1
        float xr0 = 0.f, xr1 = 0.f;
        if (c0 < DDIM){
          float m = (float)Agm[nl*136 + 59 + c0];
          xr0 = m*(float)ssx[nl*60 + c0] + (1.f-m)*(float)sxh[nl*60 + c0];
        }
        if (c1 < DDIM){
          float m = (float)Agm[nl*136 + 59 + c1];
          xr1 = m*(float)ssx[nl*60 + c1] + (1.f-m)*(float)sxh[nl*60 + c1];
        }
        a0[e] = (f16)xr0; a1[e] = (f16)xr1;
      }
      f32x4 acc = {0.f,0.f,0.f,0.f};
      acc = __builtin_amdgcn_mfma_f32_16x16x32_f16(a0, bf0, acc, 0, 0, 0);
      acc = __builtin_amdgcn_mfma_f32_16x16x32_f16(a1, bf1, acc, 0, 0, 0);
      if (nA < DDIM){
        #pragma unroll
        for (int q = 0; q < 4; q++) sxu[(mq+q)*60 + nA] = (f16)(acc[q] + fb_n);
      }
    }
    __syncthreads();

    // ---- P4: x_comb / loss / x_imp ----
    float lnum = 0.f, lden = 0.f;
    {
      float xh = (float)sxh[r0s*60+d0s], xu = (float)sxu[r0s*60+d0s];
      float bt = (float)sbt[r0s*60+d0s];
      float xc = bt*xu + (1.f-bt)*xh;
      float m  = (float)Agm[r0s*136 + 59 + d0s];
      float xv = (float)ssx[r0s*60+d0s];
      lnum = fabsf(xv - xc)*m;
      lden = m;
      float xi = m*xv + (1.f-m)*xc;
      Acat[r0s*392 + 256 + d0s] = (f16)xi;
      out_ximp[((size_t)(row0+r0s)*TT + t)*DDIM + d0s] = xi;
      if (has1){
        xh = (float)sxh[r1s*60+d1s]; xu = (float)sxu[r1s*60+d1s];
        bt = (float)sbt[r1s*60+d1s];
        xc = bt*xu + (1.f-bt)*xh;
        m  = (float)Agm[r1s*136 + 59 + d1s];
        xv = (float)ssx[r1s*60+d1s];
        lnum += fabsf(xv - xc)*m;
        lden += m;
        xi = m*xv + (1.f-m)*xc;
        Acat[r1s*392 + 256 + d1s] = (f16)xi;
        out_ximp[((size_t)(row0+r1s)*TT + t)*DDIM + d1s] = xi;
      }
    }
    #pragma unroll
    for (int off = 32; off >= 1; off >>= 1){
      lnum += __shfl_xor(lnum, off);
      lden += __shfl_xor(lden, off);
    }
    if (l == 0){ sredN[w] = lnum; sredD[w] = lden; }
    __syncthreads();
    if (tid == 0){
      float a = 0.f, b = 0.f;
      #pragma unroll
      for (int k = 0; k < 8; k++){ a += sredN[k]; b += sredD[k]; }
      atomicAdd(&ws_num[t], a); atomicAdd(&ws_den[t], b);
    }

    // ---- P5: GRU finish (kt 8-11) + gates + h update ----
    {
      f16x8 aT[4];
      #pragma unroll
      for (int k = 0; k < 4; k++)
        aT[k] = *(const f16x8*)&Acat[nl*392 + (8+k)*32 + kh];
      #pragma unroll
      for (int jj = 0; jj < 2; jj++){
        const f16* Bb = Bgru + (size_t)(2*w+jj)*36*512;
        f16x8 br[4], bz[4], bn[4];
        #pragma unroll
        for (int k = 0; k < 4; k++){
          br[k] = *(const f16x8*)&Bb[(size_t)(8+k)*512 + l*8];
          bz[k] = *(const f16x8*)&Bb[(size_t)(20+k)*512 + l*8];
          bn[k] = *(const f16x8*)&Bb[(size_t)(32+k)*512 + l*8];
        }
        f32x4 r_ = gr[jj], z_ = gz[jj];
        f32x4 gni = {0.f,0.f,0.f,0.f};
        #pragma unroll
        for (int k = 0; k < 4; k++){
          r_  = __builtin_amdgcn_mfma_f32_16x16x32_f16(aT[k], br[k], r_, 0, 0, 0);
          z_  = __builtin_amdgcn_mfma_f32_16x16x32_f16(aT[k], bz[k], z_, 0, 0, 0);
          gni = __builtin_amdgcn_mfma_f32_16x16x32_f16(aT[k], bn[k], gni, 0, 0, 0);
        }
        int j = (2*w+jj)*16 + nl;
        #pragma unroll
        for (int q = 0; q < 4; q++){
          float rg = sigm(r_[q] + br_j[jj]);
          float zg = sigm(z_[q] + bz_j[jj]);
          float ng = tanhf(gni[q] + bni_j[jj] + rg*(gnh[jj][q] + bnh_j[jj]));
          float hold = sh[(mq+q)*260 + j];
          float hn = (1.f-zg)*ng + zg*hold;
          sh[(mq+q)*260 + j] = hn;
        }
      }
    }
    __syncthreads();
  }

  // epilogue: hs write for t = TT-1
  {
    f32x4 va, vb;
    #pragma unroll
    for (int c = 0; c < 4; c++){ va[c] = sh[hrowA*260 + hj0 + c]; vb[c] = sh[hrowB*260 + hj0 + c]; }
    __builtin_nontemporal_store(va, (f32x4*)(hsA + (size_t)(TT-1)*HHID));
    __builtin_nontemporal_store(vb, (f32x4*)(hsB + (size_t)(TT-1)*HHID));
  }
}

// =====================================================================
// finalize: x_loss and classification head
// =====================================================================
__global__ __launch_bounds__(256) void final_kernel(
    const float* __restrict__ hs, const float* __restrict__ cls_W,
    const float* __restrict__ cls_b, const float* __restrict__ ws_num,
    const float* __restrict__ ws_den, float* __restrict__ out)
{
  int b = blockIdx.x*256 + threadIdx.x;
  if (b < BATCH){
    const float* hr = hs + ((size_t)b*TT + (TT-1))*HHID;
    float acc = cls_b[0];
    for (int j = 0; j < HHID; j++) acc += hr[j]*cls_W[j];
    out[OFF_YOUT + b] = acc;
    out[OFF_YSC  + b] = sigm(acc);
  }
  if (blockIdx.x == 0 && threadIdx.x == 0){
    float s = 0.f;
    for (int tt = 0; tt < TT; tt++) s += ws_num[tt]/(ws_den[tt] + 1e-5f);
    out[OFF_LOSS] = s;
  }
}

extern "C" void kernel_launch(void* const* d_in, const int* in_sizes, int n_in,
                              void* d_out, int out_size, void* d_ws, size_t ws_size,
                              hipStream_t stream)
{
  const float* x       = (const float*)d_in[0];
  const float* mask_   = (const float*)d_in[1];
  const float* deltas  = (const float*)d_in[2];
  const float* h0      = (const float*)d_in[4];
  const float* medians = (const float*)d_in[5];
  const float* W_dh    = (const float*)d_in[6];
  const float* b_dh    = (const float*)d_in[7];
  const float* W_dx    = (const float*)d_in[8];
  const float* b_dx    = (const float*)d_in[9];
  const float* hist_W  = (const float*)d_in[10];
  const float* hist_b  = (const float*)d_in[11];
  const float* feat_W  = (const float*)d_in[12];
  const float* feat_b  = (const float*)d_in[13];
  const float* wcomb_W = (const float*)d_in[14];
  const float* wcomb_b = (const float*)d_in[15];
  const float* wobs_W  = (const float*)d_in[16];
  const float* wobs_b  = (const float*)d_in[17];
  const float* W_ih    = (const float*)d_in[18];
  const float* W_hh    = (const float*)d_in[19];
  const float* b_ih    = (const float*)d_in[20];
  const float* b_hh    = (const float*)d_in[21];
  const float* cls_W   = (const float*)d_in[22];
  const float* cls_b   = (const float*)d_in[23];

  float* out    = (float*)d_out;
  float* ws_num = (float*)d_ws;              // 48 floats
  float* ws_den = ws_num + TT;               // 48 floats
  f16*   wbase  = (f16*)((char*)d_ws + 512); // f16 weight blocks

  (void)hipMemsetAsync(d_ws, 0, 512, stream);

  conv_kernel<<<166, 256, 0, stream>>>(W_dh, hist_W, feat_W, wcomb_W,
                                       W_ih, W_hh, wbase);

  decay_kernel<<<BATCH*TT/16, 256, 0, stream>>>(deltas, medians, wobs_W, wobs_b,
                                                out + OFF_DEC);

  seq_kernel<<<NWG, NTHR, 0, stream>>>(x, mask_, deltas, h0,
      b_dh, W_dx, b_dx, hist_b, feat_b, wcomb_b, b_ih, b_hh, wbase,
      out /*x_imp*/, out + OFF_HS, ws_num, ws_den);

  final_kernel<<<BATCH/256, 256, 0, stream>>>(out + OFF_HS, cls_W, cls_b,
                                              ws_num, ws_den, out);
}